// Round 7
// baseline (86.230 us; speedup 1.0000x reference)
//
#include <hip/hip_runtime.h>

#define BIGF 1e10f
#define HH 256
#define WW 256
#define BB 4
#define NPIX (BB * HH * WW)
#define MAIN_GRID (BB * HH)   // 1024 blocks, 1 row each -> 4 blocks/CU (TLP for LDS latency)

// ws layout (bytes):
//   [0 .. 1023]   double acc bins, one per 64 B (acc[i*8]) -- distinct L2 lines
//   [1024 .. 1027] unsigned done-counter
//   [2048 .. 2048+64K)  u32 gmask[2][BB][HH][8] : fg bit-masks, bit x of row y
#define WS_ACC_OFF 0
#define WS_CNT_OFF 1024
#define WS_MASK_OFF 2048
#define ACC_STRIDE 8    // doubles: 64 B apart
#define NBINS 16

// Kernel M: build packed fg masks. grid = 2 img x 4 b x 8 ytiles = 64 blocks x 256.
// Wave w handles 8 rows; per row: 4 coalesced loads + 4 ballots, lane 0 stores 32 B.
__global__ void hdt_masks_kernel(const float* __restrict__ pred,
                                 const float* __restrict__ tgt,
                                 unsigned* __restrict__ gmask,
                                 double* __restrict__ acc,
                                 unsigned* __restrict__ cnt) {
    int blk = blockIdx.x;
    int img = blk >> 5;
    int b = (blk >> 3) & 3;
    int yt = blk & 7;
    int w = threadIdx.x >> 6, lane = threadIdx.x & 63;
    if (blk == 0 && threadIdx.x == 0) {      // replaces a memset dispatch
        #pragma unroll
        for (int i = 0; i < NBINS; ++i) acc[i * ACC_STRIDE] = 0.0;
        *cnt = 0u;
    }
    const float* base = (img ? tgt : pred) + (b * HH) * WW;
    #pragma unroll 1
    for (int r = 0; r < 8; ++r) {
        int y = yt * 32 + w * 8 + r;
        const float* src = base + y * WW;
        unsigned wds[8];
        #pragma unroll
        for (int q = 0; q < 4; ++q) {
            unsigned long long bal = __ballot(src[(q << 6) + lane] > 0.5f);
            wds[2 * q] = (unsigned)bal;
            wds[2 * q + 1] = (unsigned)(bal >> 32);
        }
        if (lane == 0) {
            uint4* dst = (uint4*)(gmask + ((img * BB + b) * HH + y) * 8);
            dst[0] = make_uint4(wds[0], wds[1], wds[2], wds[3]);
            dst[1] = make_uint4(wds[4], wds[5], wds[6], wds[7]);
        }
    }
}

// Exact 1D distance^2 along a row to the nearest bit of class (mask ^ iv),
// from position x. 8 u32 words per row in LDS; near-uniform addresses per wave.
__device__ inline float row_d2(const unsigned* __restrict__ rm, int x, unsigned iv) {
    int wx = x >> 5, bx = x & 31;
    int dl = 1 << 20, dr = 1 << 20;
    unsigned m0 = rm[wx] ^ iv;                    // shared by both directions
    unsigned t = m0 & (0xFFFFFFFFu >> (31 - bx)); // bits <= bx
    int w = wx;
    while (true) {
        if (t) { int p = (w << 5) + 31 - __builtin_clz(t); dl = x - p; break; }
        if (--w < 0) break;
        t = rm[w] ^ iv;
    }
    t = m0 & (0xFFFFFFFFu << bx);                 // bits >= bx
    w = wx;
    while (true) {
        if (t) { int p = (w << 5) + __builtin_ctz(t); dr = p - x; break; }
        if (++w > 7) break;
        t = rm[w] ^ iv;
    }
    int d = dl < dr ? dl : dr;
    return (d > 255) ? BIGF : (float)(d * d);
}

// Exact expanding-window min-plus along the column; candidate rows' row-dist^2
// computed on demand by bit scan. Skipped candidates satisfy fl(f+s^2) >= s^2 >= best.
__device__ inline float col_min(const unsigned* __restrict__ mb, int y, int x, unsigned iv) {
    float best = row_d2(mb + y * 8, x, iv);
    #pragma unroll 1
    for (int s = 1; s < HH; ++s) {
        float ss = (float)(s * s);
        if (ss >= best) break;
        int ym = y - s, yp = y + s;
        if (ym >= 0) best = fminf(best, row_d2(mb + ym * 8, x, iv) + ss);
        if (yp < HH) best = fminf(best, row_d2(mb + yp * 8, x, iv) + ss);
    }
    return best;
}

// Kernel C: block = (b, y) single row, thread = x. Masks staged in 16 KB LDS,
// flags derived from staged words, fused loss + block reduce + binned atomics
// + last-block finalize. 1024 blocks -> 4 blocks/CU -> LDS latency hidden by TLP.
__launch_bounds__(256)
__global__ void hdt_main_kernel(const float* __restrict__ pred,
                                const float* __restrict__ tgt,
                                const unsigned* __restrict__ gmask,
                                double* __restrict__ acc,
                                unsigned* __restrict__ cnt,
                                float* __restrict__ out) {
    int blk = blockIdx.x;          // b*HH + y
    int b = blk >> 8;
    int y = blk & (HH - 1);
    int tid = threadIdx.x;
    __shared__ __align__(16) unsigned lmask[2][HH][8];   // 16 KB
    __shared__ unsigned wfl[4];
    {
        int img = tid >> 7, r2 = (tid & 127) << 1;       // 2 rows per thread
        const uint4* gp = (const uint4*)(gmask + ((img * BB + b) * HH + r2) * 8);
        uint4 a0 = gp[0], a1 = gp[1], a2 = gp[2], a3 = gp[3];
        uint4* lp = (uint4*)&lmask[img][r2][0];
        lp[0] = a0; lp[1] = a1; lp[2] = a2; lp[3] = a3;
        unsigned onz = a0.x | a0.y | a0.z | a0.w | a1.x | a1.y | a1.z | a1.w |
                       a2.x | a2.y | a2.z | a2.w | a3.x | a3.y | a3.z | a3.w;
        unsigned long long bal = __ballot(onz != 0u);    // waves 0-1: img0, 2-3: img1
        if ((tid & 63) == 0) wfl[tid >> 6] = (bal != 0ULL) ? 1u : 0u;
    }
    __syncthreads();
    unsigned fl_p = wfl[0] | wfl[1];
    unsigned fl_t = wfl[2] | wfl[3];

    int x = tid;
    int idx = (b * HH + y) * WW + x;
    float pv = pred[idx], tv = tgt[idx];
    float e = pv - tv;
    float errsq = e * e;
    float d2p = 0.0f, d2t = 0.0f;
    if (fl_p) {
        // query class fg -> scan for bg (invert); bg -> scan for fg
        unsigned iv = (pv > 0.5f) ? 0xFFFFFFFFu : 0u;
        float best = col_min(&lmask[0][0][0], y, x, iv);
        float dt = sqrtf(fminf(best, BIGF));
        d2p = dt * dt;
    }
    if (fl_t) {
        unsigned iv = (tv > 0.5f) ? 0xFFFFFFFFu : 0u;
        float best = col_min(&lmask[1][0][0], y, x, iv);
        float dt = sqrtf(fminf(best, BIGF));
        d2t = dt * dt;
    }
    float lsum = errsq * (d2p + d2t);

    // block reduce: wave64 shuffle then LDS across 4 waves
    #pragma unroll
    for (int off = 32; off > 0; off >>= 1)
        lsum += __shfl_down(lsum, off, 64);
    __shared__ float wsum[4];
    if ((tid & 63) == 0) wsum[tid >> 6] = lsum;
    __syncthreads();
    if (tid == 0) {
        float s2 = wsum[0] + wsum[1] + wsum[2] + wsum[3];
        atomicAdd(&acc[(blk & (NBINS - 1)) * ACC_STRIDE], (double)s2);
        __threadfence();
        if (atomicAdd(cnt, 1u) == MAIN_GRID - 1) {
            double v = 0.0;
            #pragma unroll
            for (int i = 0; i < NBINS; ++i)
                v += atomicAdd(&acc[i * ACC_STRIDE], 0.0);  // device-coherent reads
            out[0] = (float)(v * (1.0 / (double)NPIX));
        }
    }
}

extern "C" void kernel_launch(void* const* d_in, const int* in_sizes, int n_in,
                              void* d_out, int out_size, void* d_ws, size_t ws_size,
                              hipStream_t stream) {
    const float* pred = (const float*)d_in[0];
    const float* tgt = (const float*)d_in[1];
    float* out = (float*)d_out;
    char* ws = (char*)d_ws;
    double* acc = (double*)(ws + WS_ACC_OFF);
    unsigned* cnt = (unsigned*)(ws + WS_CNT_OFF);
    unsigned* gmask = (unsigned*)(ws + WS_MASK_OFF);

    hdt_masks_kernel<<<64, 256, 0, stream>>>(pred, tgt, gmask, acc, cnt);
    hdt_main_kernel<<<MAIN_GRID, 256, 0, stream>>>(pred, tgt, gmask, acc, cnt, out);
}

// Round 8
// 70.944 us; speedup vs baseline: 1.2155x; 1.2155x over previous
//
#include <hip/hip_runtime.h>

#define BIGF 1e10f
#define HH 256
#define WW 256
#define BB 4
#define NPIX (BB * HH * WW)
#define MAIN_GRID (BB * 64)   // 256 blocks x 1024 threads: 1 block/CU, 4 waves/SIMD

// ws layout (bytes):
//   [0 .. 511]    double acc bins, one per 64 B (acc[i*8]) -- distinct L2 lines
//   [512 .. 515]  unsigned done-counter
//   [2048 .. 2048+64K)  u32 gmask[2][BB][HH][8] : fg bit-masks, bit x of row y
#define WS_ACC_OFF 0
#define WS_CNT_OFF 512
#define WS_MASK_OFF 2048
#define ACC_STRIDE 8    // doubles: 64 B apart
#define NBINS 8

// Kernel M: build packed fg masks. grid = 2 img x 4 b x 8 ytiles = 64 blocks x 256.
// Wave w handles 8 rows; per row: 4 coalesced loads + 4 ballots, lane 0 stores 32 B.
__global__ void hdt_masks_kernel(const float* __restrict__ pred,
                                 const float* __restrict__ tgt,
                                 unsigned* __restrict__ gmask,
                                 double* __restrict__ acc,
                                 unsigned* __restrict__ cnt) {
    int blk = blockIdx.x;
    int img = blk >> 5;
    int b = (blk >> 3) & 3;
    int yt = blk & 7;
    int w = threadIdx.x >> 6, lane = threadIdx.x & 63;
    if (blk == 0 && threadIdx.x == 0) {      // replaces a memset dispatch
        #pragma unroll
        for (int i = 0; i < NBINS; ++i) acc[i * ACC_STRIDE] = 0.0;
        *cnt = 0u;
    }
    const float* base = (img ? tgt : pred) + (b * HH) * WW;
    #pragma unroll 1
    for (int r = 0; r < 8; ++r) {
        int y = yt * 32 + w * 8 + r;
        const float* src = base + y * WW;
        unsigned wds[8];
        #pragma unroll
        for (int q = 0; q < 4; ++q) {
            unsigned long long bal = __ballot(src[(q << 6) + lane] > 0.5f);
            wds[2 * q] = (unsigned)bal;
            wds[2 * q + 1] = (unsigned)(bal >> 32);
        }
        if (lane == 0) {
            uint4* dst = (uint4*)(gmask + ((img * BB + b) * HH + y) * 8);
            dst[0] = make_uint4(wds[0], wds[1], wds[2], wds[3]);
            dst[1] = make_uint4(wds[4], wds[5], wds[6], wds[7]);
        }
    }
}

// Exact 1D distance^2 along a row to the nearest bit of class (mask ^ iv),
// from position x. 8 u32 words per row in LDS; near-uniform addresses per wave.
__device__ inline float row_d2(const unsigned* __restrict__ rm, int x, unsigned iv) {
    int wx = x >> 5, bx = x & 31;
    int dl = 1 << 20, dr = 1 << 20;
    unsigned m0 = rm[wx] ^ iv;                    // shared by both directions
    unsigned t = m0 & (0xFFFFFFFFu >> (31 - bx)); // bits <= bx
    int w = wx;
    while (true) {
        if (t) { int p = (w << 5) + 31 - __builtin_clz(t); dl = x - p; break; }
        if (--w < 0) break;
        t = rm[w] ^ iv;
    }
    t = m0 & (0xFFFFFFFFu << bx);                 // bits >= bx
    w = wx;
    while (true) {
        if (t) { int p = (w << 5) + __builtin_ctz(t); dr = p - x; break; }
        if (++w > 7) break;
        t = rm[w] ^ iv;
    }
    int d = dl < dr ? dl : dr;
    return (d > 255) ? BIGF : (float)(d * d);
}

// Exact expanding-window min-plus along the column; candidate rows' row-dist^2
// computed on demand by bit scan. Skipped candidates satisfy fl(f+s^2) >= s^2 >= best.
__device__ inline float col_min(const unsigned* __restrict__ mb, int y, int x, unsigned iv) {
    float best = row_d2(mb + y * 8, x, iv);
    #pragma unroll 1
    for (int s = 1; s < HH; ++s) {
        float ss = (float)(s * s);
        if (ss >= best) break;
        int ym = y - s, yp = y + s;
        if (ym >= 0) best = fminf(best, row_d2(mb + ym * 8, x, iv) + ss);
        if (yp < HH) best = fminf(best, row_d2(mb + yp * 8, x, iv) + ss);
    }
    return best;
}

// Kernel C: block = (b, 4-row tile), 1024 threads (16 waves -> 4 waves/SIMD TLP).
// Masks staged once per block (1 uint4/thread, linear LDS order), flags from staged
// words, fused loss + block reduce + binned atomics + last-block finalize.
__launch_bounds__(1024, 4)
__global__ void hdt_main_kernel(const float* __restrict__ pred,
                                const float* __restrict__ tgt,
                                const unsigned* __restrict__ gmask,
                                double* __restrict__ acc,
                                unsigned* __restrict__ cnt,
                                float* __restrict__ out) {
    int blk = blockIdx.x;          // b*64 + yt
    int b = blk >> 6;
    int y0 = (blk & 63) << 2;
    int tid = threadIdx.x;
    __shared__ __align__(16) unsigned lmask[2][HH][8];   // 16 KB
    __shared__ unsigned wfl[16];
    __shared__ float wsum[16];
    {
        // thread t loads uint4 #t of this batch's mask block; LDS index == tid
        int img = tid >> 9;
        int row = (tid >> 1) & 255;
        int half = tid & 1;
        const uint4* gp = (const uint4*)gmask;
        uint4 a = gp[((img * BB + b) * HH + row) * 2 + half];
        ((uint4*)lmask)[tid] = a;
        unsigned onz = a.x | a.y | a.z | a.w;
        unsigned long long bal = __ballot(onz != 0u);    // waves 0-7: img0, 8-15: img1
        if ((tid & 63) == 0) wfl[tid >> 6] = (bal != 0ULL) ? 1u : 0u;
    }
    __syncthreads();
    unsigned fl_p = wfl[0] | wfl[1] | wfl[2] | wfl[3] | wfl[4] | wfl[5] | wfl[6] | wfl[7];
    unsigned fl_t = wfl[8] | wfl[9] | wfl[10] | wfl[11] | wfl[12] | wfl[13] | wfl[14] | wfl[15];

    int x = tid & (WW - 1);
    int y = y0 + (tid >> 8);       // wave-uniform row
    int idx = (b * HH + y) * WW + x;
    float pv = pred[idx], tv = tgt[idx];
    float e = pv - tv;
    float errsq = e * e;
    float d2p = 0.0f, d2t = 0.0f;
    if (fl_p) {
        // query class fg -> scan for bg (invert); bg -> scan for fg
        unsigned iv = (pv > 0.5f) ? 0xFFFFFFFFu : 0u;
        float best = col_min(&lmask[0][0][0], y, x, iv);
        float dt = sqrtf(fminf(best, BIGF));
        d2p = dt * dt;
    }
    if (fl_t) {
        unsigned iv = (tv > 0.5f) ? 0xFFFFFFFFu : 0u;
        float best = col_min(&lmask[1][0][0], y, x, iv);
        float dt = sqrtf(fminf(best, BIGF));
        d2t = dt * dt;
    }
    float lsum = errsq * (d2p + d2t);

    // block reduce: wave64 shuffle then LDS across 16 waves
    #pragma unroll
    for (int off = 32; off > 0; off >>= 1)
        lsum += __shfl_down(lsum, off, 64);
    if ((tid & 63) == 0) wsum[tid >> 6] = lsum;
    __syncthreads();
    if (tid == 0) {
        float s2 = 0.0f;
        #pragma unroll
        for (int i = 0; i < 16; ++i) s2 += wsum[i];
        atomicAdd(&acc[(blk & (NBINS - 1)) * ACC_STRIDE], (double)s2);
        __threadfence();
        if (atomicAdd(cnt, 1u) == MAIN_GRID - 1) {
            double v = 0.0;
            #pragma unroll
            for (int i = 0; i < NBINS; ++i)
                v += atomicAdd(&acc[i * ACC_STRIDE], 0.0);  // device-coherent reads
            out[0] = (float)(v * (1.0 / (double)NPIX));
        }
    }
}

extern "C" void kernel_launch(void* const* d_in, const int* in_sizes, int n_in,
                              void* d_out, int out_size, void* d_ws, size_t ws_size,
                              hipStream_t stream) {
    const float* pred = (const float*)d_in[0];
    const float* tgt = (const float*)d_in[1];
    float* out = (float*)d_out;
    char* ws = (char*)d_ws;
    double* acc = (double*)(ws + WS_ACC_OFF);
    unsigned* cnt = (unsigned*)(ws + WS_CNT_OFF);
    unsigned* gmask = (unsigned*)(ws + WS_MASK_OFF);

    hdt_masks_kernel<<<64, 256, 0, stream>>>(pred, tgt, gmask, acc, cnt);
    hdt_main_kernel<<<MAIN_GRID, 1024, 0, stream>>>(pred, tgt, gmask, acc, cnt, out);
}